// Round 10
// baseline (162.494 us; speedup 1.0000x reference)
//
#include <hip/hip_runtime.h>

// NRI MLP decoder, round 10: single-wave blocks (occupancy unlock) + R9 pipeline.
// B=8, N=64, T=50 (49 used), D=4, H=64, K=2 (only relation i=1), E=4032.
// Prep (3136 x 64): f16 tables V[b,t,s,k], P[b,t,n,k]; dense f32 rt table;
//   f16 weight tables W2f/B1f/B2f/B3f.
// Main (6272 x 64, ONE wave per block): wave = (b,t,4 receivers) x 64 senders.
//   Edge loop pure-register (hoisted V/P/rt/W2 frags); then the full 3-layer
//   node MLP for its 4 receivers inside the wave via a 2.3KB LDS transpose
//   buffer. __syncthreads on a 1-wave block is ~free. No cross-wave coupling.
// mfma_f32_16x16x32_f16, fp32 accumulate.

#define NB 8
#define NN 64
#define NT 50
#define NTO 49
#define ND 4
#define NE 4032

typedef _Float16 f16x8 __attribute__((ext_vector_type(8)));
typedef _Float16 f16x2 __attribute__((ext_vector_type(2)));
typedef float f32x4 __attribute__((ext_vector_type(4)));

union Frag8 { unsigned u[4]; f16x8 f; f16x2 h[4]; };

#define MFMA16(A, B, C) __builtin_amdgcn_mfma_f32_16x16x32_f16((A), (B), (C), 0, 0, 0)

// ws layout (bytes, 16B-aligned)
#define WS_VG   0u
#define WS_PG   3211264u     // 8*49*64*64*2
#define WS_RTG  6422528u     // + same
#define WS_W2F  6553600u     // + 8*64*64*4
#define WS_B1F  6561792u
#define WS_B2F  6569984u
#define WS_B3F  6578176u

// ---------------------------------------------------------------------------
// Prep: bid -> (b, t, g). g<4: V rows; g>=4: P rows. t==0 blocks build rt
// table; (b==0,t==0) blocks build f16 weight tables.
// ---------------------------------------------------------------------------
__global__ __launch_bounds__(64) void nri_prep_kernel(
    const float* __restrict__ inputs,   // (B,N,T,D)
    const float* __restrict__ rel_type, // (B,1,E,2)
    const float* __restrict__ fc1_w,    // (2,64,8)
    const float* __restrict__ fc1_b,    // (2,64)
    const float* __restrict__ fc2_w,    // (2,64,64)
    const float* __restrict__ out1_w,   // (64,68)
    const float* __restrict__ out2_w,   // (64,64)
    const float* __restrict__ out3_w,   // (4,64)
    char* __restrict__ ws)
{
  _Float16* const Vg  = (_Float16*)(ws + WS_VG);
  _Float16* const Pg  = (_Float16*)(ws + WS_PG);
  float*    const rtg = (float*)   (ws + WS_RTG);
  _Float16* const W2f = (_Float16*)(ws + WS_W2F);
  _Float16* const B1f = (_Float16*)(ws + WS_B1F);
  _Float16* const B2f = (_Float16*)(ws + WS_B2F);
  _Float16* const B3f = (_Float16*)(ws + WS_B3F);

  const int bid = blockIdx.x;
  const int g   = bid & 7;
  const int t   = (bid >> 3) % NTO;
  const int b   = bid / (8 * NTO);
  const int k   = threadIdx.x;
  const int bt64 = (b * NTO + t) * 64;

  const float4 w1r = *(const float4*)(fc1_w + 512 + k * 8);
  const float4 w1s = *(const float4*)(fc1_w + 516 + k * 8);
  const float  b1k = fc1_b[64 + k];

  if (g < 4) {
#pragma unroll
    for (int ii = 0; ii < 16; ++ii) {
      const int s = g * 16 + ii;
      const float4 x = *(const float4*)(inputs + ((b * NN + s) * NT + t) * ND);
      Vg[(bt64 + s) * 64 + k] =
          (_Float16)(w1s.x*x.x + w1s.y*x.y + w1s.z*x.z + w1s.w*x.w);
    }
  } else {
#pragma unroll
    for (int ii = 0; ii < 16; ++ii) {
      const int n = (g - 4) * 16 + ii;
      const float4 x = *(const float4*)(inputs + ((b * NN + n) * NT + t) * ND);
      Pg[(bt64 + n) * 64 + k] =
          (_Float16)(b1k + w1r.x*x.x + w1r.y*x.y + w1r.z*x.z + w1r.w*x.w);
    }
  }

  if (t == 0) {
#pragma unroll
    for (int ii = 0; ii < 8; ++ii) {
      const int n = g * 8 + ii;
      const int s = k;
      const float v = (s == n) ? 0.f
                    : rel_type[(b * NE + n * 63 + (s < n ? s : s - 1)) * 2 + 1];
      rtg[(b * 64 + n) * 64 + s] = v;
    }
  }
  if (b == 0 && t == 0) {
    if (g == 0) {
      for (int o = 0; o < 64; ++o)
        W2f[o * 64 + k] = (_Float16)fc2_w[4096 + o * 64 + k];
    } else if (g == 1) {
      for (int o = 0; o < 64; ++o)
        B1f[o * 64 + k] = (_Float16)out1_w[o * 68 + 4 + k];
    } else if (g == 2) {
      for (int o = 0; o < 64; ++o)
        B2f[o * 64 + k] = (_Float16)out2_w[o * 64 + k];
    } else if (g == 3) {
      for (int d = 0; d < 4; ++d)
        B3f[d * 64 + k] = (_Float16)out3_w[d * 64 + k];
    }
  }
}

// ---------------------------------------------------------------------------
// Main: bid -> (b, t, tile of 4 receivers). ONE 64-thread wave per block.
// ---------------------------------------------------------------------------
__global__ __launch_bounds__(64, 4) void nri_main_kernel(
    const float* __restrict__ inputs,
    const float* __restrict__ fc2_b,    // (2,64)
    const float* __restrict__ out1_w,   // (64,68)
    const float* __restrict__ out1_b,
    const float* __restrict__ out2_b,
    const float* __restrict__ out3_b,
    const char* __restrict__ ws,
    float* __restrict__ out)            // (B,N,49,4)
{
  const _Float16* const Vg  = (const _Float16*)(ws + WS_VG);
  const _Float16* const Pg  = (const _Float16*)(ws + WS_PG);
  const float*    const rtg = (const float*)   (ws + WS_RTG);
  const _Float16* const W2f = (const _Float16*)(ws + WS_W2F);
  const _Float16* const B1f = (const _Float16*)(ws + WS_B1F);
  const _Float16* const B2f = (const _Float16*)(ws + WS_B2F);
  const _Float16* const B3f = (const _Float16*)(ws + WS_B3F);

  __shared__ _Float16 TB[16 * 72];  // transpose buffer; rows 0..3 valid/phase,
                                    // rows 4..15 garbage (MFMA row-independent)

  const int bid    = blockIdx.x;
  const int tile   = bid & 15;
  const int t      = (bid >> 4) % NTO;
  const int b      = bid / (16 * NTO);
  const int n_base = tile * 4;
  const int lane = threadIdx.x;
  const int q    = lane >> 4;
  const int r    = lane & 15;
  const int bt64 = (b * NTO + t) * 64;

  // ---- hoisted: V frags for all 4 sender tiles (reg-resident through edge)
  Frag8 va[4][2];
#pragma unroll
  for (int st = 0; st < 4; ++st) {
    const _Float16* vp = Vg + (bt64 + st * 16 + r) * 64 + q * 8;
    va[st][0].f = *(const f16x8*)vp;
    va[st][1].f = *(const f16x8*)(vp + 32);
  }
  // W2 B-frags + bias
  Frag8 bfr[4][2];
  float b2l[4];
#pragma unroll
  for (int nt = 0; nt < 4; ++nt) {
    b2l[nt] = fc2_b[64 + nt * 16 + r];
    const _Float16* p = W2f + (nt * 16 + r) * 64 + q * 8;
    bfr[nt][0].f = *(const f16x8*)p;
    bfr[nt][1].f = *(const f16x8*)(p + 32);
  }

  // ---------------- edge phase: 4 receivers x 64 senders, reg-only ---------
#pragma unroll 1
  for (int np = 0; np < 4; ++np) {
    const int n = n_base + np;
    Frag8 pa0, pa1;
    {
      const _Float16* pp = Pg + (bt64 + n) * 64 + q * 8;
      pa0.f = *(const f16x8*)pp;
      pa1.f = *(const f16x8*)(pp + 32);
    }
    float4 rtv[4];
#pragma unroll
    for (int st = 0; st < 4; ++st)
      rtv[st] = *(const float4*)(rtg + (b * 64 + n) * 64 + st * 16 + q * 4);

    float m0 = 0.f, m1 = 0.f, m2 = 0.f, m3 = 0.f;
#pragma unroll
    for (int st = 0; st < 4; ++st) {
      Frag8 a0, a1;
      const f16x2 z = {(_Float16)0.f, (_Float16)0.f};
#pragma unroll
      for (int j = 0; j < 4; ++j) {
        a0.h[j] = __builtin_elementwise_max((f16x2)(pa0.h[j] + va[st][0].h[j]), z);
        a1.h[j] = __builtin_elementwise_max((f16x2)(pa1.h[j] + va[st][1].h[j]), z);
      }
      f32x4 d0 = {b2l[0], b2l[0], b2l[0], b2l[0]};
      f32x4 d1 = {b2l[1], b2l[1], b2l[1], b2l[1]};
      f32x4 d2 = {b2l[2], b2l[2], b2l[2], b2l[2]};
      f32x4 d3 = {b2l[3], b2l[3], b2l[3], b2l[3]};
      d0 = MFMA16(a0.f, bfr[0][0].f, d0); d0 = MFMA16(a1.f, bfr[0][1].f, d0);
      d1 = MFMA16(a0.f, bfr[1][0].f, d1); d1 = MFMA16(a1.f, bfr[1][1].f, d1);
      d2 = MFMA16(a0.f, bfr[2][0].f, d2); d2 = MFMA16(a1.f, bfr[2][1].f, d2);
      d3 = MFMA16(a0.f, bfr[3][0].f, d3); d3 = MFMA16(a1.f, bfr[3][1].f, d3);

      const float rtf[4] = {rtv[st].x, rtv[st].y, rtv[st].z, rtv[st].w};
#pragma unroll
      for (int e = 0; e < 4; ++e) {
        m0 = fmaf(rtf[e], fmaxf(d0[e], 0.f), m0);
        m1 = fmaf(rtf[e], fmaxf(d1[e], 0.f), m1);
        m2 = fmaf(rtf[e], fmaxf(d2[e], 0.f), m2);
        m3 = fmaf(rtf[e], fmaxf(d3[e], 0.f), m3);
      }
    }
    // cross-quad reduce; lane keeps o = lane for receiver np
    m0 += __shfl_xor(m0, 16); m0 += __shfl_xor(m0, 32);
    m1 += __shfl_xor(m1, 16); m1 += __shfl_xor(m1, 32);
    m2 += __shfl_xor(m2, 16); m2 += __shfl_xor(m2, 32);
    m3 += __shfl_xor(m3, 16); m3 += __shfl_xor(m3, 32);
    const float aval = (q == 0) ? m0 : (q == 1) ? m1 : (q == 2) ? m2 : m3;
    TB[np * 72 + lane] = (_Float16)aval;   // agg[np][o=lane]
  }
  __syncthreads();  // 1-wave block: ~free

  // ---------------- node phase (this wave's 4 receivers) ----------------
  // x rows (broadcast loads, L1-hot)
  float4 xr[4];
#pragma unroll
  for (int i = 0; i < 4; ++i)
    xr[i] = *(const float4*)(inputs + ((b * NN + n_base + i) * NT + t) * ND);

  // Layer 1: h1[n][o] = relu(b1[o] + x[n]·w1x[o] + agg[n]·W1k[o])
  {
    Frag8 A0, A1;   // A[m=r][k=q*8+j] ; rows r>=4 garbage (harmless)
    A0.f = *(const f16x8*)(TB + r * 72 + q * 8);
    A1.f = *(const f16x8*)(TB + r * 72 + 32 + q * 8);
#pragma unroll
    for (int ct = 0; ct < 4; ++ct) {
      const int o = ct * 16 + r;
      Frag8 B0, B1;
      const _Float16* pb = B1f + o * 64 + q * 8;
      B0.f = *(const f16x8*)pb;
      B1.f = *(const f16x8*)(pb + 32);
      const float  b1o = out1_b[o];
      const float4 w1x = *(const float4*)(out1_w + o * 68);
      f32x4 d = {b1o, b1o, b1o, b1o};
      d = MFMA16(A0.f, B0.f, d);
      d = MFMA16(A1.f, B1.f, d);
      if (q == 0) {   // valid rows n = reg = 0..3
#pragma unroll
        for (int reg = 0; reg < 4; ++reg) {
          const float4 x = xr[reg];
          const float hv = d[reg] + x.x*w1x.x + x.y*w1x.y + x.z*w1x.z + x.w*w1x.w;
          TB[reg * 72 + o] = (_Float16)fmaxf(hv, 0.f);
        }
      }
    }
  }
  __syncthreads();

  // Layer 2: h2 = relu(b2 + h1·W2o^T)
  {
    Frag8 A0, A1;
    A0.f = *(const f16x8*)(TB + r * 72 + q * 8);
    A1.f = *(const f16x8*)(TB + r * 72 + 32 + q * 8);
    __syncthreads();  // all reads done before overwrites below
#pragma unroll
    for (int ct = 0; ct < 4; ++ct) {
      const int o = ct * 16 + r;
      Frag8 B0, B1;
      const _Float16* pb = B2f + o * 64 + q * 8;
      B0.f = *(const f16x8*)pb;
      B1.f = *(const f16x8*)(pb + 32);
      const float b2o = out2_b[o];
      f32x4 d = {b2o, b2o, b2o, b2o};
      d = MFMA16(A0.f, B0.f, d);
      d = MFMA16(A1.f, B1.f, d);
      if (q == 0) {
#pragma unroll
        for (int reg = 0; reg < 4; ++reg)
          TB[reg * 72 + o] = (_Float16)fmaxf(d[reg], 0.f);
      }
    }
  }
  __syncthreads();

  // Layer 3: delta[n][dm] = b3[dm] + h2[n]·W3[dm]; out = x + delta
  {
    Frag8 A0, A1;
    A0.f = *(const f16x8*)(TB + r * 72 + q * 8);
    A1.f = *(const f16x8*)(TB + r * 72 + 32 + q * 8);
    Frag8 B0, B1;   // cols r>=4 duplicate rows 0..3 of out3 (discarded)
    const _Float16* pb = B3f + (r & 3) * 64 + q * 8;
    B0.f = *(const f16x8*)pb;
    B1.f = *(const f16x8*)(pb + 32);
    const float b3o = out3_b[r & 3];
    f32x4 d = {b3o, b3o, b3o, b3o};
    d = MFMA16(A0.f, B0.f, d);
    d = MFMA16(A1.f, B1.f, d);
    if (q == 0 && r < 4) {   // D[row=reg][col=r]
#pragma unroll
      for (int reg = 0; reg < 4; ++reg) {
        const float xs = inputs[((b * NN + n_base + reg) * NT + t) * ND + r];
        out[((b * NN + n_base + reg) * NTO + t) * ND + r] = xs + d[reg];
      }
    }
  }
}

extern "C" void kernel_launch(void* const* d_in, const int* in_sizes, int n_in,
                              void* d_out, int out_size, void* d_ws, size_t ws_size,
                              hipStream_t stream) {
  const float* inputs   = (const float*)d_in[0];
  const float* rel_type = (const float*)d_in[1];
  const float* fc1_w  = (const float*)d_in[4];
  const float* fc1_b  = (const float*)d_in[5];
  const float* fc2_w  = (const float*)d_in[6];
  const float* fc2_b  = (const float*)d_in[7];
  const float* out1_w = (const float*)d_in[8];
  const float* out1_b = (const float*)d_in[9];
  const float* out2_w = (const float*)d_in[10];
  const float* out2_b = (const float*)d_in[11];
  const float* out3_w = (const float*)d_in[12];
  const float* out3_b = (const float*)d_in[13];
  float* out = (float*)d_out;
  char* ws = (char*)d_ws;

  nri_prep_kernel<<<NB * NTO * 8, 64, 0, stream>>>(
      inputs, rel_type, fc1_w, fc1_b, fc2_w, out1_w, out2_w, out3_w, ws);
  nri_main_kernel<<<NB * NTO * 16, 64, 0, stream>>>(
      inputs, fc2_b, out1_w, out1_b, out2_b, out3_b, ws, out);
}

// Round 11
// 129.757 us; speedup vs baseline: 1.2523x; 1.2523x over previous
//
#include <hip/hip_runtime.h>

// NRI MLP decoder, round 11: R10 structure, spill fix.
// ONLY change vs R10: __launch_bounds__(64) without the min-waves arg.
// R10's (64,4) forced a 64-VGPR budget against a ~110-reg working set ->
// 48 spilled VGPRs -> 77MB scratch writes/dispatch (memory-bound disaster).
// B=8, N=64, T=50 (49 used), D=4, H=64, K=2 (only relation i=1), E=4032.
// Prep (3136 x 64): f16 tables V/P; dense f32 rt table; f16 weight tables.
// Main (6272 x 64, one wave per block): wave = (b,t,4 receivers) x 64 senders,
//   pure-register edge loop, in-wave 3-layer node MLP via 2.3KB LDS.
// mfma_f32_16x16x32_f16, fp32 accumulate.

#define NB 8
#define NN 64
#define NT 50
#define NTO 49
#define ND 4
#define NE 4032

typedef _Float16 f16x8 __attribute__((ext_vector_type(8)));
typedef _Float16 f16x2 __attribute__((ext_vector_type(2)));
typedef float f32x4 __attribute__((ext_vector_type(4)));

union Frag8 { unsigned u[4]; f16x8 f; f16x2 h[4]; };

#define MFMA16(A, B, C) __builtin_amdgcn_mfma_f32_16x16x32_f16((A), (B), (C), 0, 0, 0)

// ws layout (bytes, 16B-aligned)
#define WS_VG   0u
#define WS_PG   3211264u     // 8*49*64*64*2
#define WS_RTG  6422528u     // + same
#define WS_W2F  6553600u     // + 8*64*64*4
#define WS_B1F  6561792u
#define WS_B2F  6569984u
#define WS_B3F  6578176u

// ---------------------------------------------------------------------------
// Prep: bid -> (b, t, g). g<4: V rows; g>=4: P rows. t==0 blocks build rt
// table; (b==0,t==0) blocks build f16 weight tables.
// ---------------------------------------------------------------------------
__global__ __launch_bounds__(64) void nri_prep_kernel(
    const float* __restrict__ inputs,   // (B,N,T,D)
    const float* __restrict__ rel_type, // (B,1,E,2)
    const float* __restrict__ fc1_w,    // (2,64,8)
    const float* __restrict__ fc1_b,    // (2,64)
    const float* __restrict__ fc2_w,    // (2,64,64)
    const float* __restrict__ out1_w,   // (64,68)
    const float* __restrict__ out2_w,   // (64,64)
    const float* __restrict__ out3_w,   // (4,64)
    char* __restrict__ ws)
{
  _Float16* const Vg  = (_Float16*)(ws + WS_VG);
  _Float16* const Pg  = (_Float16*)(ws + WS_PG);
  float*    const rtg = (float*)   (ws + WS_RTG);
  _Float16* const W2f = (_Float16*)(ws + WS_W2F);
  _Float16* const B1f = (_Float16*)(ws + WS_B1F);
  _Float16* const B2f = (_Float16*)(ws + WS_B2F);
  _Float16* const B3f = (_Float16*)(ws + WS_B3F);

  const int bid = blockIdx.x;
  const int g   = bid & 7;
  const int t   = (bid >> 3) % NTO;
  const int b   = bid / (8 * NTO);
  const int k   = threadIdx.x;
  const int bt64 = (b * NTO + t) * 64;

  const float4 w1r = *(const float4*)(fc1_w + 512 + k * 8);
  const float4 w1s = *(const float4*)(fc1_w + 516 + k * 8);
  const float  b1k = fc1_b[64 + k];

  if (g < 4) {
#pragma unroll
    for (int ii = 0; ii < 16; ++ii) {
      const int s = g * 16 + ii;
      const float4 x = *(const float4*)(inputs + ((b * NN + s) * NT + t) * ND);
      Vg[(bt64 + s) * 64 + k] =
          (_Float16)(w1s.x*x.x + w1s.y*x.y + w1s.z*x.z + w1s.w*x.w);
    }
  } else {
#pragma unroll
    for (int ii = 0; ii < 16; ++ii) {
      const int n = (g - 4) * 16 + ii;
      const float4 x = *(const float4*)(inputs + ((b * NN + n) * NT + t) * ND);
      Pg[(bt64 + n) * 64 + k] =
          (_Float16)(b1k + w1r.x*x.x + w1r.y*x.y + w1r.z*x.z + w1r.w*x.w);
    }
  }

  if (t == 0) {
#pragma unroll
    for (int ii = 0; ii < 8; ++ii) {
      const int n = g * 8 + ii;
      const int s = k;
      const float v = (s == n) ? 0.f
                    : rel_type[(b * NE + n * 63 + (s < n ? s : s - 1)) * 2 + 1];
      rtg[(b * 64 + n) * 64 + s] = v;
    }
  }
  if (b == 0 && t == 0) {
    if (g == 0) {
      for (int o = 0; o < 64; ++o)
        W2f[o * 64 + k] = (_Float16)fc2_w[4096 + o * 64 + k];
    } else if (g == 1) {
      for (int o = 0; o < 64; ++o)
        B1f[o * 64 + k] = (_Float16)out1_w[o * 68 + 4 + k];
    } else if (g == 2) {
      for (int o = 0; o < 64; ++o)
        B2f[o * 64 + k] = (_Float16)out2_w[o * 64 + k];
    } else if (g == 3) {
      for (int d = 0; d < 4; ++d)
        B3f[d * 64 + k] = (_Float16)out3_w[d * 64 + k];
    }
  }
}

// ---------------------------------------------------------------------------
// Main: bid -> (b, t, tile of 4 receivers). ONE 64-thread wave per block.
// Plain __launch_bounds__(64): let the allocator take ~96-128 VGPRs, no spill.
// ---------------------------------------------------------------------------
__global__ __launch_bounds__(64) void nri_main_kernel(
    const float* __restrict__ inputs,
    const float* __restrict__ fc2_b,    // (2,64)
    const float* __restrict__ out1_w,   // (64,68)
    const float* __restrict__ out1_b,
    const float* __restrict__ out2_b,
    const float* __restrict__ out3_b,
    const char* __restrict__ ws,
    float* __restrict__ out)            // (B,N,49,4)
{
  const _Float16* const Vg  = (const _Float16*)(ws + WS_VG);
  const _Float16* const Pg  = (const _Float16*)(ws + WS_PG);
  const float*    const rtg = (const float*)   (ws + WS_RTG);
  const _Float16* const W2f = (const _Float16*)(ws + WS_W2F);
  const _Float16* const B1f = (const _Float16*)(ws + WS_B1F);
  const _Float16* const B2f = (const _Float16*)(ws + WS_B2F);
  const _Float16* const B3f = (const _Float16*)(ws + WS_B3F);

  __shared__ _Float16 TB[16 * 72];  // transpose buffer; rows 0..3 valid/phase

  const int bid    = blockIdx.x;
  const int tile   = bid & 15;
  const int t      = (bid >> 4) % NTO;
  const int b      = bid / (16 * NTO);
  const int n_base = tile * 4;
  const int lane = threadIdx.x;
  const int q    = lane >> 4;
  const int r    = lane & 15;
  const int bt64 = (b * NTO + t) * 64;

  // ---- hoisted: V frags for all 4 sender tiles (reg-resident through edge)
  Frag8 va[4][2];
#pragma unroll
  for (int st = 0; st < 4; ++st) {
    const _Float16* vp = Vg + (bt64 + st * 16 + r) * 64 + q * 8;
    va[st][0].f = *(const f16x8*)vp;
    va[st][1].f = *(const f16x8*)(vp + 32);
  }
  // W2 B-frags + bias
  Frag8 bfr[4][2];
  float b2l[4];
#pragma unroll
  for (int nt = 0; nt < 4; ++nt) {
    b2l[nt] = fc2_b[64 + nt * 16 + r];
    const _Float16* p = W2f + (nt * 16 + r) * 64 + q * 8;
    bfr[nt][0].f = *(const f16x8*)p;
    bfr[nt][1].f = *(const f16x8*)(p + 32);
  }

  // ---------------- edge phase: 4 receivers x 64 senders, reg-only ---------
#pragma unroll 1
  for (int np = 0; np < 4; ++np) {
    const int n = n_base + np;
    Frag8 pa0, pa1;
    {
      const _Float16* pp = Pg + (bt64 + n) * 64 + q * 8;
      pa0.f = *(const f16x8*)pp;
      pa1.f = *(const f16x8*)(pp + 32);
    }
    float4 rtv[4];
#pragma unroll
    for (int st = 0; st < 4; ++st)
      rtv[st] = *(const float4*)(rtg + (b * 64 + n) * 64 + st * 16 + q * 4);

    float m0 = 0.f, m1 = 0.f, m2 = 0.f, m3 = 0.f;
#pragma unroll
    for (int st = 0; st < 4; ++st) {
      Frag8 a0, a1;
      const f16x2 z = {(_Float16)0.f, (_Float16)0.f};
#pragma unroll
      for (int j = 0; j < 4; ++j) {
        a0.h[j] = __builtin_elementwise_max((f16x2)(pa0.h[j] + va[st][0].h[j]), z);
        a1.h[j] = __builtin_elementwise_max((f16x2)(pa1.h[j] + va[st][1].h[j]), z);
      }
      f32x4 d0 = {b2l[0], b2l[0], b2l[0], b2l[0]};
      f32x4 d1 = {b2l[1], b2l[1], b2l[1], b2l[1]};
      f32x4 d2 = {b2l[2], b2l[2], b2l[2], b2l[2]};
      f32x4 d3 = {b2l[3], b2l[3], b2l[3], b2l[3]};
      d0 = MFMA16(a0.f, bfr[0][0].f, d0); d0 = MFMA16(a1.f, bfr[0][1].f, d0);
      d1 = MFMA16(a0.f, bfr[1][0].f, d1); d1 = MFMA16(a1.f, bfr[1][1].f, d1);
      d2 = MFMA16(a0.f, bfr[2][0].f, d2); d2 = MFMA16(a1.f, bfr[2][1].f, d2);
      d3 = MFMA16(a0.f, bfr[3][0].f, d3); d3 = MFMA16(a1.f, bfr[3][1].f, d3);

      const float rtf[4] = {rtv[st].x, rtv[st].y, rtv[st].z, rtv[st].w};
#pragma unroll
      for (int e = 0; e < 4; ++e) {
        m0 = fmaf(rtf[e], fmaxf(d0[e], 0.f), m0);
        m1 = fmaf(rtf[e], fmaxf(d1[e], 0.f), m1);
        m2 = fmaf(rtf[e], fmaxf(d2[e], 0.f), m2);
        m3 = fmaf(rtf[e], fmaxf(d3[e], 0.f), m3);
      }
    }
    // cross-quad reduce; lane keeps o = lane for receiver np
    m0 += __shfl_xor(m0, 16); m0 += __shfl_xor(m0, 32);
    m1 += __shfl_xor(m1, 16); m1 += __shfl_xor(m1, 32);
    m2 += __shfl_xor(m2, 16); m2 += __shfl_xor(m2, 32);
    m3 += __shfl_xor(m3, 16); m3 += __shfl_xor(m3, 32);
    const float aval = (q == 0) ? m0 : (q == 1) ? m1 : (q == 2) ? m2 : m3;
    TB[np * 72 + lane] = (_Float16)aval;   // agg[np][o=lane]
  }
  __syncthreads();  // 1-wave block: ~free

  // ---------------- node phase (this wave's 4 receivers) ----------------
  float4 xr[4];
#pragma unroll
  for (int i = 0; i < 4; ++i)
    xr[i] = *(const float4*)(inputs + ((b * NN + n_base + i) * NT + t) * ND);

  // Layer 1: h1[n][o] = relu(b1[o] + x[n]·w1x[o] + agg[n]·W1k[o])
  {
    Frag8 A0, A1;   // A[m=r][k=q*8+j]; rows r>=4 garbage (harmless)
    A0.f = *(const f16x8*)(TB + r * 72 + q * 8);
    A1.f = *(const f16x8*)(TB + r * 72 + 32 + q * 8);
#pragma unroll
    for (int ct = 0; ct < 4; ++ct) {
      const int o = ct * 16 + r;
      Frag8 B0, B1;
      const _Float16* pb = B1f + o * 64 + q * 8;
      B0.f = *(const f16x8*)pb;
      B1.f = *(const f16x8*)(pb + 32);
      const float  b1o = out1_b[o];
      const float4 w1x = *(const float4*)(out1_w + o * 68);
      f32x4 d = {b1o, b1o, b1o, b1o};
      d = MFMA16(A0.f, B0.f, d);
      d = MFMA16(A1.f, B1.f, d);
      if (q == 0) {   // valid rows n = reg = 0..3
#pragma unroll
        for (int reg = 0; reg < 4; ++reg) {
          const float4 x = xr[reg];
          const float hv = d[reg] + x.x*w1x.x + x.y*w1x.y + x.z*w1x.z + x.w*w1x.w;
          TB[reg * 72 + o] = (_Float16)fmaxf(hv, 0.f);
        }
      }
    }
  }
  __syncthreads();

  // Layer 2: h2 = relu(b2 + h1·W2o^T)
  {
    Frag8 A0, A1;
    A0.f = *(const f16x8*)(TB + r * 72 + q * 8);
    A1.f = *(const f16x8*)(TB + r * 72 + 32 + q * 8);
    __syncthreads();  // all reads done before overwrites below
#pragma unroll
    for (int ct = 0; ct < 4; ++ct) {
      const int o = ct * 16 + r;
      Frag8 B0, B1;
      const _Float16* pb = B2f + o * 64 + q * 8;
      B0.f = *(const f16x8*)pb;
      B1.f = *(const f16x8*)(pb + 32);
      const float b2o = out2_b[o];
      f32x4 d = {b2o, b2o, b2o, b2o};
      d = MFMA16(A0.f, B0.f, d);
      d = MFMA16(A1.f, B1.f, d);
      if (q == 0) {
#pragma unroll
        for (int reg = 0; reg < 4; ++reg)
          TB[reg * 72 + o] = (_Float16)fmaxf(d[reg], 0.f);
      }
    }
  }
  __syncthreads();

  // Layer 3: delta[n][dm] = b3[dm] + h2[n]·W3[dm]; out = x + delta
  {
    Frag8 A0, A1;
    A0.f = *(const f16x8*)(TB + r * 72 + q * 8);
    A1.f = *(const f16x8*)(TB + r * 72 + 32 + q * 8);
    Frag8 B0, B1;   // cols r>=4 duplicate rows 0..3 of out3 (discarded)
    const _Float16* pb = B3f + (r & 3) * 64 + q * 8;
    B0.f = *(const f16x8*)pb;
    B1.f = *(const f16x8*)(pb + 32);
    const float b3o = out3_b[r & 3];
    f32x4 d = {b3o, b3o, b3o, b3o};
    d = MFMA16(A0.f, B0.f, d);
    d = MFMA16(A1.f, B1.f, d);
    if (q == 0 && r < 4) {   // D[row=reg][col=r]
#pragma unroll
      for (int reg = 0; reg < 4; ++reg) {
        const float xs = inputs[((b * NN + n_base + reg) * NT + t) * ND + r];
        out[((b * NN + n_base + reg) * NTO + t) * ND + r] = xs + d[reg];
      }
    }
  }
}

extern "C" void kernel_launch(void* const* d_in, const int* in_sizes, int n_in,
                              void* d_out, int out_size, void* d_ws, size_t ws_size,
                              hipStream_t stream) {
  const float* inputs   = (const float*)d_in[0];
  const float* rel_type = (const float*)d_in[1];
  const float* fc1_w  = (const float*)d_in[4];
  const float* fc1_b  = (const float*)d_in[5];
  const float* fc2_w  = (const float*)d_in[6];
  const float* fc2_b  = (const float*)d_in[7];
  const float* out1_w = (const float*)d_in[8];
  const float* out1_b = (const float*)d_in[9];
  const float* out2_w = (const float*)d_in[10];
  const float* out2_b = (const float*)d_in[11];
  const float* out3_w = (const float*)d_in[12];
  const float* out3_b = (const float*)d_in[13];
  float* out = (float*)d_out;
  char* ws = (char*)d_ws;

  nri_prep_kernel<<<NB * NTO * 8, 64, 0, stream>>>(
      inputs, rel_type, fc1_w, fc1_b, fc2_w, out1_w, out2_w, out3_w, ws);
  nri_main_kernel<<<NB * NTO * 16, 64, 0, stream>>>(
      inputs, fc2_b, out1_w, out1_b, out2_b, out3_b, ws, out);
}